// Round 13
// baseline (4896.868 us; speedup 1.0000x reference)
//
#include <hip/hip_runtime.h>

#define NN 100000
#define F_IN 512
#define HID 256
#define NCLS 64
#define NHOPS 3
#define NE 3200000
#define NB 782              // ceil(NN/128) buckets of 128 dst nodes
#define NBP 800             // padded counter array size
#define CHUNK 6400          // edges per fill block (25 rounds x 256 threads)
#define FBLK_PER_HOP 500    // 500*6400 == NE exactly

typedef unsigned short u16;
typedef unsigned int u32;
typedef __attribute__((ext_vector_type(8))) short bf16x8;
typedef __attribute__((ext_vector_type(4))) float f32x4;
typedef __attribute__((ext_vector_type(4))) unsigned int u32x4;

__device__ __forceinline__ u16 f2bf(float f) {
    unsigned int u = __float_as_uint(f);
    u += 0x7fffu + ((u >> 16) & 1u);   // RNE
    return (u16)(u >> 16);
}
__device__ __forceinline__ float bf2f(u16 h) {
    return __uint_as_float(((unsigned int)h) << 16);
}

// ---------------------------------------------------------------------------
// weights -> bf16 transposed
// ---------------------------------------------------------------------------
__global__ void convert_weights(const float* __restrict__ w1,
                                const float* __restrict__ w2,
                                u16* __restrict__ w1t, u16* __restrict__ w2t) {
    int t = blockIdx.x * 256 + threadIdx.x;
    if (t < F_IN * HID) {
        int k = t / HID, n = t % HID;
        w1t[n * F_IN + k] = f2bf(w1[t]);
    } else if (t < F_IN * HID + HID * NCLS) {
        int i = t - F_IN * HID;
        int k = i / NCLS, n = i % NCLS;
        w2t[n * HID + k] = f2bf(w2[i]);
    }
}

// ---------------------------------------------------------------------------
// GEMM1: h = relu(x @ W1 + b1) bf16. 128x256 tile, 8 waves. (unchanged)
// ---------------------------------------------------------------------------
__global__ __launch_bounds__(512) void gemm1_kernel(
    const float* __restrict__ x, const u16* __restrict__ w1t,
    const float* __restrict__ b1, u16* __restrict__ h)
{
    __shared__ u16 As[128][72];
    __shared__ u16 Bs[256][72];
    const int tid  = threadIdx.x;
    const int lane = tid & 63;
    const int wid  = tid >> 6;
    const int wr   = wid >> 2;
    const int wc   = wid & 3;
    const int row0 = blockIdx.x * 128;

    f32x4 acc[4][4] = {};

    const int ar  = tid >> 2;
    const int aks = (tid & 3) * 16;
    int agrow = row0 + ar; if (agrow >= NN) agrow = NN - 1;
    const float* asrc = x + (size_t)agrow * F_IN + aks;

    const int bn  = tid >> 1;
    const int bks = (tid & 1) * 32;
    const u16* bsrc = w1t + bn * F_IN + bks;

    for (int k0 = 0; k0 < F_IN; k0 += 64) {
        alignas(16) u16 tmp[16];
        #pragma unroll
        for (int i = 0; i < 4; ++i) {
            f32x4 v = *(const f32x4*)(asrc + k0 + i * 4);
            tmp[i*4+0] = f2bf(v[0]); tmp[i*4+1] = f2bf(v[1]);
            tmp[i*4+2] = f2bf(v[2]); tmp[i*4+3] = f2bf(v[3]);
        }
        *(u32x4*)&As[ar][aks]     = *(const u32x4*)&tmp[0];
        *(u32x4*)&As[ar][aks + 8] = *(const u32x4*)&tmp[8];
        #pragma unroll
        for (int i = 0; i < 4; ++i)
            *(u32x4*)&Bs[bn][bks + i*8] = *(const u32x4*)(bsrc + k0 + i*8);
        __syncthreads();

        #pragma unroll
        for (int kk = 0; kk < 2; ++kk) {
            const int kb = kk*32 + (lane >> 4)*8;
            bf16x8 a[4], b[4];
            #pragma unroll
            for (int m = 0; m < 4; ++m)
                a[m] = *(const bf16x8*)&As[wr*64 + m*16 + (lane & 15)][kb];
            #pragma unroll
            for (int n = 0; n < 4; ++n)
                b[n] = *(const bf16x8*)&Bs[wc*64 + n*16 + (lane & 15)][kb];
            #pragma unroll
            for (int m = 0; m < 4; ++m)
                #pragma unroll
                for (int n = 0; n < 4; ++n)
                    acc[m][n] = __builtin_amdgcn_mfma_f32_16x16x32_bf16(
                        a[m], b[n], acc[m][n], 0, 0, 0);
        }
        __syncthreads();
    }

    const int cl    = lane & 15;
    const int rbase = (lane >> 4) * 4;
    #pragma unroll
    for (int n = 0; n < 4; ++n) {
        const int col  = wc*64 + n*16 + cl;
        const float bias = b1[col];
        #pragma unroll
        for (int m = 0; m < 4; ++m) {
            #pragma unroll
            for (int rr = 0; rr < 4; ++rr) {
                const int grow = row0 + wr*64 + m*16 + rbase + rr;
                if (grow < NN) {
                    float v = acc[m][n][rr] + bias;
                    h[(size_t)grow * HID + col] = f2bf(v > 0.f ? v : 0.f);
                }
            }
        }
    }
}

// ---------------------------------------------------------------------------
// GEMM2: zb = bf16(h @ W2 + b2). 128x64 tile, 4 waves. (unchanged)
// ---------------------------------------------------------------------------
__global__ __launch_bounds__(256) void gemm2_kernel(
    const u16* __restrict__ h, const u16* __restrict__ w2t,
    const float* __restrict__ b2, u16* __restrict__ zb)
{
    __shared__ u16 As[128][72];
    __shared__ u16 Bs[64][72];
    const int tid  = threadIdx.x;
    const int lane = tid & 63;
    const int wid  = tid >> 6;
    const int row0 = blockIdx.x * 128;

    f32x4 acc[2][4] = {};

    const int ar  = tid >> 1;
    const int aks = (tid & 1) * 32;
    int agrow = row0 + ar; if (agrow >= NN) agrow = NN - 1;
    const u16* asrc = h + (size_t)agrow * HID + aks;

    const int bn  = tid >> 2;
    const int bks = (tid & 3) * 16;
    const u16* bsrc = w2t + bn * HID + bks;

    for (int k0 = 0; k0 < HID; k0 += 64) {
        #pragma unroll
        for (int i = 0; i < 4; ++i)
            *(u32x4*)&As[ar][aks + i*8] = *(const u32x4*)(asrc + k0 + i*8);
        #pragma unroll
        for (int i = 0; i < 2; ++i)
            *(u32x4*)&Bs[bn][bks + i*8] = *(const u32x4*)(bsrc + k0 + i*8);
        __syncthreads();

        #pragma unroll
        for (int kk = 0; kk < 2; ++kk) {
            const int kb = kk*32 + (lane >> 4)*8;
            bf16x8 a[2], b[4];
            #pragma unroll
            for (int m = 0; m < 2; ++m)
                a[m] = *(const bf16x8*)&As[wid*32 + m*16 + (lane & 15)][kb];
            #pragma unroll
            for (int n = 0; n < 4; ++n)
                b[n] = *(const bf16x8*)&Bs[n*16 + (lane & 15)][kb];
            #pragma unroll
            for (int m = 0; m < 2; ++m)
                #pragma unroll
                for (int n = 0; n < 4; ++n)
                    acc[m][n] = __builtin_amdgcn_mfma_f32_16x16x32_bf16(
                        a[m], b[n], acc[m][n], 0, 0, 0);
        }
        __syncthreads();
    }

    const int cl    = lane & 15;
    const int rbase = (lane >> 4) * 4;
    #pragma unroll
    for (int n = 0; n < 4; ++n) {
        const int col = n*16 + cl;
        const float bias = b2[col];
        #pragma unroll
        for (int m = 0; m < 2; ++m) {
            #pragma unroll
            for (int rr = 0; rr < 4; ++rr) {
                const int grow = row0 + wid*32 + m*16 + rbase + rr;
                if (grow < NN)
                    zb[(size_t)grow * NCLS + col] = f2bf(acc[m][n][rr] + bias);
            }
        }
    }
}

// ---------------------------------------------------------------------------
// bucket_count: per-block LDS histogram over 782 buckets (dst>>7), one
// global atomic per nonzero bucket per block.
// ---------------------------------------------------------------------------
__global__ __launch_bounds__(256) void bucket_count(const int* __restrict__ eidx,
                                                    u32* __restrict__ gcnt) {
    __shared__ u32 sh[NBP];
    const int tid = threadIdx.x;
    for (int i = tid; i < NBP; i += 256) sh[i] = 0;
    __syncthreads();
    const int t0 = blockIdx.x * 256 + tid;
    const int stride = gridDim.x * 256;
    #pragma unroll
    for (int l = 0; l < NHOPS; ++l) {
        const int* dstp = eidx + (size_t)l * 2 * NE + NE;
        for (int e = t0; e < NE; e += stride)
            atomicAdd(&sh[dstp[e] >> 7], 1u);
    }
    __syncthreads();
    for (int i = tid; i < NBP; i += 256)
        if (sh[i]) atomicAdd(&gcnt[i], sh[i]);
}

// ---------------------------------------------------------------------------
// bucket_scan: exclusive scan of 782 counts -> gptr[783], gcur init.
// ---------------------------------------------------------------------------
__global__ __launch_bounds__(256) void bucket_scan(const u32* __restrict__ gcnt,
                                                   u32* __restrict__ gptr,
                                                   u32* __restrict__ gcur) {
    __shared__ u32 s[NBP];
    const int tid = threadIdx.x;
    for (int i = tid; i < NBP; i += 256) s[i] = gcnt[i];
    __syncthreads();
    if (tid == 0) {
        u32 run = 0;
        for (int i = 0; i < NB; ++i) { u32 v = s[i]; s[i] = run; run += v; }
        s[NB] = run;
    }
    __syncthreads();
    for (int i = tid; i <= NB; i += 256) {
        gptr[i] = s[i];
        if (i < NB) gcur[i] = s[i];
    }
}

// ---------------------------------------------------------------------------
// bucket_fill: LDS-staged bucket scatter. Each block: stage CHUNK edges,
// count per bucket, reserve per-bucket global ranges (1 atomic/bucket/block),
// write grouped -> contiguous single-XCD runs (kills the 15x write amp).
// Payload: meta u32 = src | (dst&127)<<20 ; coef f16.
// ---------------------------------------------------------------------------
__global__ __launch_bounds__(256) void bucket_fill(
    const int* __restrict__ eidx, const float* __restrict__ att,
    const float* __restrict__ pw, u32* __restrict__ gcur,
    u32* __restrict__ srtdm, _Float16* __restrict__ coefg)
{
    __shared__ u32 bufm[CHUNK];          // 25.6 KB
    __shared__ u16 bufB[CHUNK];          // 12.8 KB
    __shared__ _Float16 bufc[CHUNK];     // 12.8 KB
    __shared__ u32 hist[NBP], cur[NBP], gbase[NBP];  // 9.6 KB
    const int tid  = threadIdx.x;
    const int l    = blockIdx.x / FBLK_PER_HOP;
    const int base = (blockIdx.x % FBLK_PER_HOP) * CHUNK;

    for (int i = tid; i < NBP; i += 256) { hist[i] = 0; cur[i] = 0; }
    __syncthreads();

    const int* srcp = eidx + (size_t)l * 2 * NE;
    const int* dstp = srcp + NE;
    const float* al = att + (size_t)l * NE;
    const float w = pw[l + 1];

    #pragma unroll 5
    for (int r = 0; r < CHUNK / 256; ++r) {
        const int e = base + r * 256 + tid;
        const int s = srcp[e];
        const int d = dstp[e];
        const int b = d >> 7;
        bufm[r*256+tid] = (u32)s | ((u32)(d & 127) << 20);
        bufB[r*256+tid] = (u16)b;
        bufc[r*256+tid] = (_Float16)(w * al[e]);
        atomicAdd(&hist[b], 1u);
    }
    __syncthreads();

    for (int i = tid; i < NBP; i += 256) {
        const u32 hh = hist[i];
        if (hh) gbase[i] = atomicAdd(&gcur[i], hh);
    }
    __syncthreads();

    #pragma unroll 5
    for (int r = 0; r < CHUNK / 256; ++r) {
        const int j = r*256+tid;
        const int b = bufB[j];
        const u32 lp = atomicAdd(&cur[b], 1u);
        const u32 pos = gbase[b] + lp;
        srtdm[pos] = bufm[j];
        coefg[pos] = bufc[j];
    }
}

// ---------------------------------------------------------------------------
// bucket_accum: one block per bucket (128 nodes), LDS f32 accumulator 32KB.
// Waves stream bucket edges (lane = channel), 8 z-gathers in flight,
// ds_add_f32 LDS atomics. Fused pw0-term + log_softmax epilogue.
// ---------------------------------------------------------------------------
__global__ __launch_bounds__(512) void bucket_accum(
    const u32* __restrict__ gptr, const u32* __restrict__ srtdm,
    const _Float16* __restrict__ coefg, const u16* __restrict__ zb,
    const float* __restrict__ pw, float* __restrict__ out)
{
    __shared__ float accS[128 * NCLS];   // 32 KB
    const int tid  = threadIdx.x;
    const int lane = tid & 63;
    const int w    = tid >> 6;           // 8 waves
    const int b    = blockIdx.x;

    for (int i = tid; i < 128 * NCLS; i += 512) accS[i] = 0.f;
    __syncthreads();

    const int p0 = gptr[b], p1 = gptr[b + 1];

    for (int e0 = p0 + w * 64; e0 < p1; e0 += 512) {
        const int idx = e0 + lane;
        u32 m = 0; float c = 0.f;
        if (idx < p1) { m = srtdm[idx]; c = (float)coefg[idx]; }
        const int cnt = min(64, p1 - e0);
        int k = 0;
        for (; k + 8 <= cnt; k += 8) {
            u32 m0=__shfl(m,k),   m1=__shfl(m,k+1), m2=__shfl(m,k+2), m3=__shfl(m,k+3);
            u32 m4=__shfl(m,k+4), m5=__shfl(m,k+5), m6=__shfl(m,k+6), m7=__shfl(m,k+7);
            float c0=__shfl(c,k),   c1=__shfl(c,k+1), c2=__shfl(c,k+2), c3=__shfl(c,k+3);
            float c4=__shfl(c,k+4), c5=__shfl(c,k+5), c6=__shfl(c,k+6), c7=__shfl(c,k+7);
            float z0 = bf2f(zb[(size_t)(m0 & 0xFFFFF) * NCLS + lane]);
            float z1 = bf2f(zb[(size_t)(m1 & 0xFFFFF) * NCLS + lane]);
            float z2 = bf2f(zb[(size_t)(m2 & 0xFFFFF) * NCLS + lane]);
            float z3 = bf2f(zb[(size_t)(m3 & 0xFFFFF) * NCLS + lane]);
            float z4 = bf2f(zb[(size_t)(m4 & 0xFFFFF) * NCLS + lane]);
            float z5 = bf2f(zb[(size_t)(m5 & 0xFFFFF) * NCLS + lane]);
            float z6 = bf2f(zb[(size_t)(m6 & 0xFFFFF) * NCLS + lane]);
            float z7 = bf2f(zb[(size_t)(m7 & 0xFFFFF) * NCLS + lane]);
            atomicAdd(&accS[((m0 >> 20) & 127) * NCLS + lane], c0 * z0);
            atomicAdd(&accS[((m1 >> 20) & 127) * NCLS + lane], c1 * z1);
            atomicAdd(&accS[((m2 >> 20) & 127) * NCLS + lane], c2 * z2);
            atomicAdd(&accS[((m3 >> 20) & 127) * NCLS + lane], c3 * z3);
            atomicAdd(&accS[((m4 >> 20) & 127) * NCLS + lane], c4 * z4);
            atomicAdd(&accS[((m5 >> 20) & 127) * NCLS + lane], c5 * z5);
            atomicAdd(&accS[((m6 >> 20) & 127) * NCLS + lane], c6 * z6);
            atomicAdd(&accS[((m7 >> 20) & 127) * NCLS + lane], c7 * z7);
        }
        for (; k < cnt; ++k) {
            u32 mk = __shfl(m, k); float ck = __shfl(c, k);
            float zk = bf2f(zb[(size_t)(mk & 0xFFFFF) * NCLS + lane]);
            atomicAdd(&accS[((mk >> 20) & 127) * NCLS + lane], ck * zk);
        }
    }
    __syncthreads();

    const float pw0 = pw[0];
    for (int loc = w; loc < 128; loc += 8) {
        const int n = b * 128 + loc;
        if (n >= NN) continue;                     // wave-uniform
        float v = pw0 * bf2f(zb[(size_t)n * NCLS + lane]) + accS[loc * NCLS + lane];
        float mm = v;
        #pragma unroll
        for (int off = 32; off; off >>= 1) mm = fmaxf(mm, __shfl_xor(mm, off));
        float ss = __expf(v - mm);
        #pragma unroll
        for (int off = 32; off; off >>= 1) ss += __shfl_xor(ss, off);
        out[(size_t)n * NCLS + lane] = v - mm - __logf(ss);
    }
}

// ---------------------------------------------------------------------------
extern "C" void kernel_launch(void* const* d_in, const int* in_sizes, int n_in,
                              void* d_out, int out_size, void* d_ws, size_t ws_size,
                              hipStream_t stream) {
    const float* x   = (const float*)d_in[0];
    const float* w1  = (const float*)d_in[1];
    const float* b1  = (const float*)d_in[2];
    const float* w2  = (const float*)d_in[3];
    const float* b2  = (const float*)d_in[4];
    const float* att = (const float*)d_in[5];
    const float* pw  = (const float*)d_in[6];
    const int* eidx  = (const int*)d_in[7];
    float* out = (float*)d_out;

    char* ws = (char*)d_ws;
    size_t off = 0;
    auto take = [&](size_t sz) { char* p = ws + off; off = (off + sz + 255) & ~(size_t)255; return p; };

    u16* w1t   = (u16*)take(F_IN * HID * 2);             // 0.26 MB
    u16* w2t   = (u16*)take(HID * NCLS * 2);             // 0.03 MB
    u32* gcnt  = (u32*)take(NBP * 4);
    u32* gptr  = (u32*)take(NBP * 4);
    u32* gcur  = (u32*)take(NBP * 4);
    u16* zb    = (u16*)take((size_t)NN * NCLS * 2);      // 12.8 MB
    // shared region: h (51.2 MB, dead after gemm2) overlaid by srtdm (38.4 MB)
    // + coefg (19.2 MB) = 57.6 MB total
    char* region = take((size_t)NHOPS * NE * 4 + (size_t)NHOPS * NE * 2);
    u16* h       = (u16*)region;
    u32* srtdm   = (u32*)region;
    _Float16* coefg = (_Float16*)(region + (size_t)NHOPS * NE * 4);

    hipMemsetAsync(gcnt, 0, NBP * 4, stream);
    convert_weights<<<(F_IN*HID + HID*NCLS + 255) / 256, 256, 0, stream>>>(w1, w2, w1t, w2t);

    const int nblk_m = (NN + 127) / 128;                 // 782
    gemm1_kernel<<<nblk_m, 512, 0, stream>>>(x, w1t, b1, h);
    gemm2_kernel<<<nblk_m, 256, 0, stream>>>(h, w2t, b2, zb);

    bucket_count<<<512, 256, 0, stream>>>(eidx, gcnt);
    bucket_scan<<<1, 256, 0, stream>>>(gcnt, gptr, gcur);
    bucket_fill<<<NHOPS * FBLK_PER_HOP, 256, 0, stream>>>(eidx, att, pw, gcur, srtdm, coefg); // after gemm2 (aliases h)
    bucket_accum<<<NB, 512, 0, stream>>>(gptr, srtdm, coefg, zb, pw, out);
}